// Round 6
// baseline (438.947 us; speedup 1.0000x reference)
//
#include <hip/hip_runtime.h>

#define N_NODES 50000
#define N_EDGES 800000
#define DIM 128
#define NCLS 40
#define SCAN_BLK 196   // ceil(50000/256)
#define FILL_T 200000  // threads for fill_csr, 4 edges each

typedef __bf16 bf16x8_t __attribute__((ext_vector_type(8)));
typedef unsigned short us8_t __attribute__((ext_vector_type(8)));
typedef unsigned short us4_t __attribute__((ext_vector_type(4)));
typedef float f32x4_t __attribute__((ext_vector_type(4)));

static __device__ __forceinline__ float b2f(unsigned short h) {
    unsigned u = ((unsigned)h) << 16;
    return __builtin_bit_cast(float, u);
}
static __device__ __forceinline__ unsigned short f2b(float f) {
    unsigned u = __builtin_bit_cast(unsigned, f);
    u += 0x7FFFu + ((u >> 16) & 1u);   // RNE; values finite O(1)
    return (unsigned short)(u >> 16);
}

// ---------------- fused: degree count + f32->bf16 shadow of h ----------------
__global__ __launch_bounds__(256) void prep_kernel(const int* __restrict__ dst,
                                                   int* __restrict__ deg,
                                                   const float* __restrict__ hin,
                                                   unsigned short* __restrict__ hb16) {
    int t = blockIdx.x * 256 + threadIdx.x;
    if (t < N_EDGES) atomicAdd(&deg[dst[t]], 1);
    size_t e0 = (size_t)t * 8;
    f32x4_t v0 = *(const f32x4_t*)(hin + e0);
    f32x4_t v1 = *(const f32x4_t*)(hin + e0 + 4);
    us8_t o;
    #pragma unroll
    for (int j = 0; j < 4; ++j) { o[j] = f2b(v0[j]); o[4 + j] = f2b(v1[j]); }
    *(us8_t*)(hb16 + e0) = o;
}

// ---------------- hierarchical exclusive scan of deg ----------------
__global__ __launch_bounds__(256) void scan_partial(const int* __restrict__ deg,
                                                    int* __restrict__ partial) {
    __shared__ int lds[256];
    int tid = threadIdx.x;
    int idx = blockIdx.x * 256 + tid;
    lds[tid] = (idx < N_NODES) ? deg[idx] : 0;
    __syncthreads();
    #pragma unroll
    for (int off = 128; off > 0; off >>= 1) {
        if (tid < off) lds[tid] += lds[tid + off];
        __syncthreads();
    }
    if (tid == 0) partial[blockIdx.x] = lds[0];
}

__global__ __launch_bounds__(256) void scan_blocks(const int* __restrict__ partial,
                                                   int* __restrict__ blk_off) {
    __shared__ int lds[256];
    int tid = threadIdx.x;
    lds[tid] = (tid < SCAN_BLK) ? partial[tid] : 0;
    __syncthreads();
    #pragma unroll
    for (int off = 1; off < 256; off <<= 1) {
        int v = lds[tid];
        int add = (tid >= off) ? lds[tid - off] : 0;
        __syncthreads();
        lds[tid] = v + add;
        __syncthreads();
    }
    if (tid < SCAN_BLK) blk_off[tid] = (tid == 0) ? 0 : lds[tid - 1];
}

__global__ __launch_bounds__(256) void scan_final(const int* __restrict__ deg,
                                                  const int* __restrict__ blk_off,
                                                  int* __restrict__ rs,
                                                  int* __restrict__ cursor,
                                                  float* __restrict__ dinv) {
    __shared__ int lds[256];
    int tid = threadIdx.x;
    int idx = blockIdx.x * 256 + tid;
    int d = (idx < N_NODES) ? deg[idx] : 0;
    lds[tid] = d;
    __syncthreads();
    #pragma unroll
    for (int off = 1; off < 256; off <<= 1) {
        int v = lds[tid];
        int add = (tid >= off) ? lds[tid - off] : 0;
        __syncthreads();
        lds[tid] = v + add;
        __syncthreads();
    }
    if (idx < N_NODES) {
        int excl = blk_off[blockIdx.x] + lds[tid] - d;
        rs[idx] = excl;
        cursor[idx] = excl;
        dinv[idx] = (d > 0) ? (1.0f / (float)d) : 0.0f;
    }
}

// ---------------- CSR fill: 4 edges/thread, 4 returning atomics in flight ----------------
// entry = src (16b, N<65536) | bf16(mask) << 16
__global__ __launch_bounds__(256) void fill_csr(const int* __restrict__ src,
                                                const int* __restrict__ dst,
                                                const float* __restrict__ mask,
                                                int* __restrict__ cursor,
                                                unsigned* __restrict__ csr) {
    int t = blockIdx.x * 256 + threadIdx.x;
    if (t >= FILL_T) return;
    int e0 = t, e1 = t + FILL_T, e2 = t + 2 * FILL_T, e3 = t + 3 * FILL_T;
    // all loads first (coalesced per segment)
    int d0 = dst[e0], d1 = dst[e1], d2 = dst[e2], d3 = dst[e3];
    unsigned s0 = (unsigned)src[e0] | ((unsigned)f2b(mask[e0]) << 16);
    unsigned s1 = (unsigned)src[e1] | ((unsigned)f2b(mask[e1]) << 16);
    unsigned s2 = (unsigned)src[e2] | ((unsigned)f2b(mask[e2]) << 16);
    unsigned s3 = (unsigned)src[e3] | ((unsigned)f2b(mask[e3]) << 16);
    // four independent returning atomics — 4x MLP on the round-trip
    int p0 = atomicAdd(&cursor[d0], 1);
    int p1 = atomicAdd(&cursor[d1], 1);
    int p2 = atomicAdd(&cursor[d2], 1);
    int p3 = atomicAdd(&cursor[d3], 1);
    csr[p0] = s0;
    csr[p1] = s1;
    csr[p2] = s2;
    csr[p3] = s3;
}

// ---------------- mean aggregation: bf16 gather + f32 residual ----------------
__global__ __launch_bounds__(256) void agg_kernel(const unsigned short* __restrict__ xb,
                                                  const float* __restrict__ x,
                                                  float* __restrict__ xin,
                                                  const int* __restrict__ rs,
                                                  const int* __restrict__ deg,
                                                  const float* __restrict__ dinv,
                                                  const unsigned* __restrict__ csr) {
    int lane = threadIdx.x & 63;
    int node = blockIdx.x * 4 + (threadIdx.x >> 6);
    if (node >= N_NODES) return;
    int cnt = deg[node];
    int start = rs[node];
    float acc0 = 0.f, acc1 = 0.f;
    for (int base = 0; base < cnt; base += 16) {
        int nb = cnt - base;
        if (nb > 16) nb = 16;
        unsigned pk = 0;
        if (lane < nb) pk = csr[start + base + lane];
        unsigned vv[16];
        float mm[16];
        #pragma unroll
        for (int j = 0; j < 16; ++j) {
            unsigned p = (unsigned)__builtin_amdgcn_readlane((int)pk, j);  // 0 for j>=nb
            mm[j] = b2f((unsigned short)(p >> 16));
            vv[j] = *(const unsigned*)(xb + (size_t)(p & 0xFFFFu) * DIM + lane * 2);
        }
        #pragma unroll
        for (int j = 0; j < 16; ++j) {
            acc0 += mm[j] * b2f((unsigned short)(vv[j] & 0xFFFFu));
            acc1 += mm[j] * b2f((unsigned short)(vv[j] >> 16));
        }
    }
    float di = dinv[node];
    float2 xp = *(const float2*)(x + (size_t)node * DIM + lane * 2);
    float2 o;
    o.x = xp.x + acc0 * di;
    o.y = xp.y + acc1 * di;
    *(float2*)(xin + (size_t)node * DIM + lane * 2) = o;
}

// ---------------- GEMM [N,128]x[128,128] + BN + ReLU, split-bf16 MFMA ----------------
__global__ __launch_bounds__(256) void gemm128_bn_relu(const float* __restrict__ xin,
                                                       const float* __restrict__ W,
                                                       const float* __restrict__ bias,
                                                       const float* __restrict__ gam,
                                                       const float* __restrict__ bet,
                                                       const float* __restrict__ rm,
                                                       const float* __restrict__ rv,
                                                       float* __restrict__ out,
                                                       unsigned short* __restrict__ outb) {
    __shared__ unsigned short WTh[128 * 136];   // hi(W^T), +8 pad
    __shared__ unsigned short WTl[128 * 136];   // lo(W^T)
    int tid = threadIdx.x;
    #pragma unroll
    for (int it = 0; it < 16; ++it) {
        int flat = (it * 256 + tid) * 4;       // element in row-major W [k][n]
        int k = flat >> 7;
        int n0 = flat & 127;
        f32x4_t v = *(const f32x4_t*)(W + flat);
        #pragma unroll
        for (int j = 0; j < 4; ++j) {
            unsigned short hi = f2b(v[j]);
            float lo = v[j] - b2f(hi);
            WTh[(n0 + j) * 136 + k] = hi;
            WTl[(n0 + j) * 136 + k] = f2b(lo);
        }
    }
    __syncthreads();

    int wave = tid >> 6, lane = tid & 63;
    int m = lane & 15, quad = lane >> 4;
    int rbase = blockIdx.x * 64 + wave * 16;
    int arow = rbase + m;
    const float* ap = xin + (size_t)(arow < N_NODES ? arow : 0) * DIM;

    us8_t ah[4], al[4];
    #pragma unroll
    for (int kt = 0; kt < 4; ++kt) {
        f32x4_t p0 = *(const f32x4_t*)(ap + kt * 32 + quad * 8);
        f32x4_t p1 = *(const f32x4_t*)(ap + kt * 32 + quad * 8 + 4);
        #pragma unroll
        for (int j = 0; j < 4; ++j) {
            unsigned short h0 = f2b(p0[j]);
            unsigned short h1 = f2b(p1[j]);
            ah[kt][j] = h0;
            ah[kt][4 + j] = h1;
            al[kt][j] = f2b(p0[j] - b2f(h0));
            al[kt][4 + j] = f2b(p1[j] - b2f(h1));
        }
    }

    f32x4_t acc[8] = {};
    #pragma unroll
    for (int kt = 0; kt < 4; ++kt) {
        #pragma unroll
        for (int nt = 0; nt < 8; ++nt) {
            int boff = (nt * 16 + m) * 136 + kt * 32 + quad * 8;
            us8_t bh = *(const us8_t*)(&WTh[boff]);
            us8_t bl = *(const us8_t*)(&WTl[boff]);
            acc[nt] = __builtin_amdgcn_mfma_f32_16x16x32_bf16(
                __builtin_bit_cast(bf16x8_t, ah[kt]),
                __builtin_bit_cast(bf16x8_t, bh), acc[nt], 0, 0, 0);
            acc[nt] = __builtin_amdgcn_mfma_f32_16x16x32_bf16(
                __builtin_bit_cast(bf16x8_t, ah[kt]),
                __builtin_bit_cast(bf16x8_t, bl), acc[nt], 0, 0, 0);
            acc[nt] = __builtin_amdgcn_mfma_f32_16x16x32_bf16(
                __builtin_bit_cast(bf16x8_t, al[kt]),
                __builtin_bit_cast(bf16x8_t, bh), acc[nt], 0, 0, 0);
        }
    }

    #pragma unroll
    for (int nt = 0; nt < 8; ++nt) {
        int j = nt * 16 + m;
        float bj = bias[j];
        float sc = gam[j] * rsqrtf(rv[j] + 1e-5f);
        float sh = bet[j] - rm[j] * sc;
        #pragma unroll
        for (int i = 0; i < 4; ++i) {
            int r = rbase + quad * 4 + i;
            if (r < N_NODES) {
                float z = fmaxf((acc[nt][i] + bj) * sc + sh, 0.f);
                out[(size_t)r * DIM + j] = z;
                outb[(size_t)r * DIM + j] = f2b(z);
            }
        }
    }
}

// ---------------- fused final: h3 = relu(BN((h2+agg)@w2+b2)); out = (h2@wp+bp+h3)*0.5 ----------------
__global__ __launch_bounds__(256) void fused_final(const float* __restrict__ xin2,
                                                   const float* __restrict__ h2,
                                                   const float* __restrict__ w2,
                                                   const float* __restrict__ wp,
                                                   const float* __restrict__ b2,
                                                   const float* __restrict__ g2,
                                                   const float* __restrict__ be2,
                                                   const float* __restrict__ rm2,
                                                   const float* __restrict__ rv2,
                                                   const float* __restrict__ bp,
                                                   float* __restrict__ out) {
    __shared__ unsigned short W2Th[48 * 136];
    __shared__ unsigned short W2Tl[48 * 136];
    __shared__ unsigned short WPTh[48 * 136];
    __shared__ unsigned short WPTl[48 * 136];
    int tid = threadIdx.x;
    #pragma unroll
    for (int it = 0; it < 24; ++it) {
        int flat = it * 256 + tid;             // 48*128 = 6144
        int n = flat >> 7, k = flat & 127;
        float v2 = 0.f, vp = 0.f;
        if (n < NCLS) {
            v2 = w2[k * NCLS + n];
            vp = wp[k * NCLS + n];
        }
        unsigned short h2b = f2b(v2);
        unsigned short hpb = f2b(vp);
        W2Th[n * 136 + k] = h2b;
        W2Tl[n * 136 + k] = f2b(v2 - b2f(h2b));
        WPTh[n * 136 + k] = hpb;
        WPTl[n * 136 + k] = f2b(vp - b2f(hpb));
    }
    __syncthreads();

    int wave = tid >> 6, lane = tid & 63;
    int m = lane & 15, quad = lane >> 4;
    int rbase = blockIdx.x * 64 + wave * 16;
    int arow = rbase + m;
    size_t rowoff = (size_t)(arow < N_NODES ? arow : 0) * DIM;
    const float* ap2 = xin2 + rowoff;
    const float* aph = h2 + rowoff;

    us8_t a2h[4], a2l[4], ahh[4], ahl[4];
    #pragma unroll
    for (int kt = 0; kt < 4; ++kt) {
        f32x4_t p0 = *(const f32x4_t*)(ap2 + kt * 32 + quad * 8);
        f32x4_t p1 = *(const f32x4_t*)(ap2 + kt * 32 + quad * 8 + 4);
        f32x4_t q0 = *(const f32x4_t*)(aph + kt * 32 + quad * 8);
        f32x4_t q1 = *(const f32x4_t*)(aph + kt * 32 + quad * 8 + 4);
        #pragma unroll
        for (int j = 0; j < 4; ++j) {
            unsigned short h0 = f2b(p0[j]), h1 = f2b(p1[j]);
            a2h[kt][j] = h0; a2h[kt][4 + j] = h1;
            a2l[kt][j] = f2b(p0[j] - b2f(h0));
            a2l[kt][4 + j] = f2b(p1[j] - b2f(h1));
            unsigned short g0 = f2b(q0[j]), g1 = f2b(q1[j]);
            ahh[kt][j] = g0; ahh[kt][4 + j] = g1;
            ahl[kt][j] = f2b(q0[j] - b2f(g0));
            ahl[kt][4 + j] = f2b(q1[j] - b2f(g1));
        }
    }

    f32x4_t acc2[3] = {};
    f32x4_t accp[3] = {};
    #pragma unroll
    for (int kt = 0; kt < 4; ++kt) {
        #pragma unroll
        for (int nt = 0; nt < 3; ++nt) {
            int boff = (nt * 16 + m) * 136 + kt * 32 + quad * 8;
            us8_t b2hv = *(const us8_t*)(&W2Th[boff]);
            us8_t b2lv = *(const us8_t*)(&W2Tl[boff]);
            us8_t bphv = *(const us8_t*)(&WPTh[boff]);
            us8_t bplv = *(const us8_t*)(&WPTl[boff]);
            acc2[nt] = __builtin_amdgcn_mfma_f32_16x16x32_bf16(
                __builtin_bit_cast(bf16x8_t, a2h[kt]),
                __builtin_bit_cast(bf16x8_t, b2hv), acc2[nt], 0, 0, 0);
            acc2[nt] = __builtin_amdgcn_mfma_f32_16x16x32_bf16(
                __builtin_bit_cast(bf16x8_t, a2h[kt]),
                __builtin_bit_cast(bf16x8_t, b2lv), acc2[nt], 0, 0, 0);
            acc2[nt] = __builtin_amdgcn_mfma_f32_16x16x32_bf16(
                __builtin_bit_cast(bf16x8_t, a2l[kt]),
                __builtin_bit_cast(bf16x8_t, b2hv), acc2[nt], 0, 0, 0);
            accp[nt] = __builtin_amdgcn_mfma_f32_16x16x32_bf16(
                __builtin_bit_cast(bf16x8_t, ahh[kt]),
                __builtin_bit_cast(bf16x8_t, bphv), accp[nt], 0, 0, 0);
            accp[nt] = __builtin_amdgcn_mfma_f32_16x16x32_bf16(
                __builtin_bit_cast(bf16x8_t, ahh[kt]),
                __builtin_bit_cast(bf16x8_t, bplv), accp[nt], 0, 0, 0);
            accp[nt] = __builtin_amdgcn_mfma_f32_16x16x32_bf16(
                __builtin_bit_cast(bf16x8_t, ahl[kt]),
                __builtin_bit_cast(bf16x8_t, bphv), accp[nt], 0, 0, 0);
        }
    }

    #pragma unroll
    for (int nt = 0; nt < 3; ++nt) {
        int j = nt * 16 + m;
        int jc = (j < NCLS) ? j : (NCLS - 1);
        float b2j = b2[jc];
        float sc = g2[jc] * rsqrtf(rv2[jc] + 1e-5f);
        float sh = be2[jc] - rm2[jc] * sc;
        float bpj = bp[jc];
        #pragma unroll
        for (int i = 0; i < 4; ++i) {
            int r = rbase + quad * 4 + i;
            if (r < N_NODES && j < NCLS) {
                float z = fmaxf((acc2[nt][i] + b2j) * sc + sh, 0.f);
                float p = accp[nt][i] + bpj;
                out[(size_t)r * NCLS + j] = (p + z) * 0.5f;
            }
        }
    }
}

extern "C" void kernel_launch(void* const* d_in, const int* in_sizes, int n_in,
                              void* d_out, int out_size, void* d_ws, size_t ws_size,
                              hipStream_t stream) {
    const float* h    = (const float*)d_in[0];
    const int* esrc   = (const int*)d_in[1];
    const int* edst   = (const int*)d_in[2];
    const float* mask = (const float*)d_in[3];
    const float* w0   = (const float*)d_in[4];
    const float* b0   = (const float*)d_in[5];
    const float* g0   = (const float*)d_in[6];
    const float* be0  = (const float*)d_in[7];
    const float* rm0  = (const float*)d_in[8];
    const float* rv0  = (const float*)d_in[9];
    const float* w1   = (const float*)d_in[10];
    const float* b1   = (const float*)d_in[11];
    const float* g1   = (const float*)d_in[12];
    const float* be1  = (const float*)d_in[13];
    const float* rm1  = (const float*)d_in[14];
    const float* rv1  = (const float*)d_in[15];
    const float* w2   = (const float*)d_in[16];
    const float* b2   = (const float*)d_in[17];
    const float* g2   = (const float*)d_in[18];
    const float* be2  = (const float*)d_in[19];
    const float* rm2  = (const float*)d_in[20];
    const float* rv2  = (const float*)d_in[21];
    const float* wp   = (const float*)d_in[22];
    const float* bp   = (const float*)d_in[23];

    char* ws = (char*)d_ws;
    size_t off = 0;
    auto alloc = [&](size_t bytes) {
        char* p = ws + off;
        off = (off + bytes + 255) & ~(size_t)255;
        return p;
    };
    int* deg      = (int*)alloc(N_NODES * 4);
    int* rs       = (int*)alloc(N_NODES * 4);
    int* cursor   = (int*)alloc(N_NODES * 4);
    float* dinv   = (float*)alloc(N_NODES * 4);
    int* partial  = (int*)alloc(256 * 4);
    int* blk_off  = (int*)alloc(256 * 4);
    unsigned* csr = (unsigned*)alloc((size_t)N_EDGES * 4);
    float* xin    = (float*)alloc((size_t)N_NODES * DIM * 4);
    float* hb     = (float*)alloc((size_t)N_NODES * DIM * 4);
    unsigned short* xb16 = (unsigned short*)alloc((size_t)N_NODES * DIM * 2);
    unsigned short* hb16 = (unsigned short*)alloc((size_t)N_NODES * DIM * 2);

    hipMemsetAsync(deg, 0, N_NODES * 4, stream);

    const int EB = (N_EDGES + 255) / 256;     // 3125
    const int FB = (FILL_T + 255) / 256;      // 782
    const int AB = (N_NODES + 3) / 4;
    const int GB = (N_NODES + 63) / 64;

    prep_kernel<<<EB, 256, 0, stream>>>(edst, deg, h, xb16);
    scan_partial<<<SCAN_BLK, 256, 0, stream>>>(deg, partial);
    scan_blocks<<<1, 256, 0, stream>>>(partial, blk_off);
    scan_final<<<SCAN_BLK, 256, 0, stream>>>(deg, blk_off, rs, cursor, dinv);
    fill_csr<<<FB, 256, 0, stream>>>(esrc, edst, mask, cursor, csr);

    // layer 0
    agg_kernel<<<AB, 256, 0, stream>>>(xb16, h, xin, rs, deg, dinv, csr);
    gemm128_bn_relu<<<GB, 256, 0, stream>>>(xin, w0, b0, g0, be0, rm0, rv0, hb, hb16);
    // layer 1
    agg_kernel<<<AB, 256, 0, stream>>>(hb16, hb, xin, rs, deg, dinv, csr);
    gemm128_bn_relu<<<GB, 256, 0, stream>>>(xin, w1, b1, g1, be1, rm1, rv1, hb, hb16);
    // layer 2 + predict, fused
    agg_kernel<<<AB, 256, 0, stream>>>(hb16, hb, xin, rs, deg, dinv, csr);
    fused_final<<<GB, 256, 0, stream>>>(xin, hb, w2, wp, b2, g2, be2, rm2, rv2, bp,
                                        (float*)d_out);
}

// Round 7
// 415.569 us; speedup vs baseline: 1.0563x; 1.0563x over previous
//
#include <hip/hip_runtime.h>

#define N_NODES 50000
#define N_EDGES 800000
#define DIM 128
#define NCLS 40

// chunked CSR build
#define NCHUNK 128
#define CE 6250            // NCHUNK*CE == N_EDGES exactly
#define HALF_N 25088       // nodes per half (2*WHALF)
#define WHALF 12544        // packed u32 words per half (= 49*256)
#define SCAN_B 98          // cscan/scan_final blocks (2 halves * 49)
#define N_PAD 50432        // >= 2*HALF_N padded node arrays

typedef __bf16 bf16x8_t __attribute__((ext_vector_type(8)));
typedef unsigned short us8_t __attribute__((ext_vector_type(8)));
typedef float f32x4_t __attribute__((ext_vector_type(4)));

static __device__ __forceinline__ float b2f(unsigned short h) {
    unsigned u = ((unsigned)h) << 16;
    return __builtin_bit_cast(float, u);
}
static __device__ __forceinline__ unsigned short f2b(float f) {
    unsigned u = __builtin_bit_cast(unsigned, f);
    u += 0x7FFFu + ((u >> 16) & 1u);   // RNE; values finite O(1)
    return (unsigned short)(u >> 16);
}

// ---------------- f32 -> bf16 shadow of h ----------------
__global__ __launch_bounds__(256) void to_bf16(const float* __restrict__ in,
                                               unsigned short* __restrict__ out) {
    size_t e0 = ((size_t)blockIdx.x * 256 + threadIdx.x) * 8;   // 3125*256*8 = 6.4M exact
    f32x4_t v0 = *(const f32x4_t*)(in + e0);
    f32x4_t v1 = *(const f32x4_t*)(in + e0 + 4);
    us8_t o;
    #pragma unroll
    for (int j = 0; j < 4; ++j) { o[j] = f2b(v0[j]); o[4 + j] = f2b(v1[j]); }
    *(us8_t*)(out + e0) = o;
}

// ---------------- per-chunk per-node edge counts (LDS atomics, no global atomics) ----------------
// cnt layout: [half][chunk][WHALF] u32, each word = two 16-bit node counts
__global__ __launch_bounds__(256) void chunk_count(const int* __restrict__ dst,
                                                   unsigned* __restrict__ cnt) {
    __shared__ unsigned lds[WHALF];   // 50 KB
    int c = blockIdx.x, tid = threadIdx.x;
    for (int h = 0; h < 2; ++h) {
        for (int w = tid; w < WHALF; w += 256) lds[w] = 0;
        __syncthreads();
        int base = c * CE;
        for (int k = tid; k < CE; k += 256) {
            int local = dst[base + k] - h * HALF_N;
            if (local >= 0 && local < HALF_N)
                atomicAdd(&lds[local >> 1], 1u << ((local & 1) * 16));
        }
        __syncthreads();
        unsigned* out = cnt + ((size_t)(h * NCHUNK + c)) * WHALF;
        for (int w = tid; w < WHALF; w += 256) out[w] = lds[w];
        __syncthreads();
    }
}

// ---------------- scan over chunk axis: counts -> per-chunk offsets; emits packed deg + block partials ----------------
__global__ __launch_bounds__(256) void cscan(unsigned* __restrict__ cnt,
                                             unsigned* __restrict__ degp,
                                             int* __restrict__ partial) {
    __shared__ int lds[256];
    int b = blockIdx.x;
    int h = b / 49;
    int w = (b % 49) * 256 + threadIdx.x;
    unsigned acc = 0;
    for (int c = 0; c < NCHUNK; ++c) {
        size_t idx = ((size_t)(h * NCHUNK + c)) * WHALF + w;
        unsigned v = cnt[idx];
        cnt[idx] = acc;          // exclusive prefix (packed halves, no cross-carry: each sum < 65536)
        acc += v;
    }
    degp[h * WHALF + w] = acc;
    lds[threadIdx.x] = (int)(acc & 0xFFFFu) + (int)(acc >> 16);
    __syncthreads();
    #pragma unroll
    for (int off = 128; off > 0; off >>= 1) {
        if (threadIdx.x < off) lds[threadIdx.x] += lds[threadIdx.x + off];
        __syncthreads();
    }
    if (threadIdx.x == 0) partial[b] = lds[0];
}

__global__ __launch_bounds__(128) void scan_blocks(const int* __restrict__ partial,
                                                   int* __restrict__ blk_off) {
    __shared__ int lds[128];
    int tid = threadIdx.x;
    lds[tid] = (tid < SCAN_B) ? partial[tid] : 0;
    __syncthreads();
    #pragma unroll
    for (int off = 1; off < 128; off <<= 1) {
        int v = lds[tid];
        int add = (tid >= off) ? lds[tid - off] : 0;
        __syncthreads();
        lds[tid] = v + add;
        __syncthreads();
    }
    if (tid < SCAN_B) blk_off[tid] = (tid == 0) ? 0 : lds[tid - 1];
}

// ---------------- final node-axis scan: rs / deg / dinv ----------------
__global__ __launch_bounds__(256) void scan_final(const unsigned* __restrict__ degp,
                                                  const int* __restrict__ blk_off,
                                                  int* __restrict__ rs,
                                                  int* __restrict__ deg,
                                                  float* __restrict__ dinv) {
    __shared__ int lds[256];
    int b = blockIdx.x;
    int h = b / 49;
    int tid = threadIdx.x;
    int w = (b % 49) * 256 + tid;
    unsigned dp = degp[h * WHALF + w];
    int lo = (int)(dp & 0xFFFFu), hi = (int)(dp >> 16);
    int s = lo + hi;
    lds[tid] = s;
    __syncthreads();
    #pragma unroll
    for (int off = 1; off < 256; off <<= 1) {
        int v = lds[tid];
        int add = (tid >= off) ? lds[tid - off] : 0;
        __syncthreads();
        lds[tid] = v + add;
        __syncthreads();
    }
    int excl = blk_off[b] + lds[tid] - s;
    int n0 = h * HALF_N + 2 * w;
    rs[n0] = excl;
    rs[n0 + 1] = excl + lo;
    deg[n0] = lo;
    deg[n0 + 1] = hi;
    dinv[n0] = (lo > 0) ? (1.0f / (float)lo) : 0.0f;
    dinv[n0 + 1] = (hi > 0) ? (1.0f / (float)hi) : 0.0f;
}

// ---------------- CSR fill: rank via LDS returning atomics, one plain store per edge ----------------
__global__ __launch_bounds__(256) void fill2(const int* __restrict__ src,
                                             const int* __restrict__ dst,
                                             const float* __restrict__ mask,
                                             const unsigned* __restrict__ cnt,
                                             const int* __restrict__ rs,
                                             unsigned* __restrict__ csr) {
    __shared__ unsigned cur[WHALF];   // 50 KB
    int c = blockIdx.x, tid = threadIdx.x;
    for (int h = 0; h < 2; ++h) {
        const unsigned* off = cnt + ((size_t)(h * NCHUNK + c)) * WHALF;
        for (int w = tid; w < WHALF; w += 256) cur[w] = off[w];
        __syncthreads();
        int base = c * CE;
        for (int k = tid; k < CE; k += 256) {
            int e = base + k;
            int d = dst[e];
            int local = d - h * HALF_N;
            if (local >= 0 && local < HALF_N) {
                unsigned sm = (unsigned)src[e] | ((unsigned)f2b(mask[e]) << 16);
                int sh = (local & 1) * 16;
                unsigned old = atomicAdd(&cur[local >> 1], 1u << sh);
                int rank = (int)((old >> sh) & 0xFFFFu);
                csr[rs[d] + rank] = sm;
            }
        }
        __syncthreads();
    }
}

// ---------------- mean aggregation: bf16 gather + f32 residual ----------------
__global__ __launch_bounds__(256) void agg_kernel(const unsigned short* __restrict__ xb,
                                                  const float* __restrict__ x,
                                                  float* __restrict__ xin,
                                                  const int* __restrict__ rs,
                                                  const int* __restrict__ deg,
                                                  const float* __restrict__ dinv,
                                                  const unsigned* __restrict__ csr) {
    int lane = threadIdx.x & 63;
    int node = blockIdx.x * 4 + (threadIdx.x >> 6);
    if (node >= N_NODES) return;
    int cnt = deg[node];
    int start = rs[node];
    float acc0 = 0.f, acc1 = 0.f;
    for (int base = 0; base < cnt; base += 16) {
        int nb = cnt - base;
        if (nb > 16) nb = 16;
        unsigned pk = 0;
        if (lane < nb) pk = csr[start + base + lane];
        unsigned vv[16];
        float mm[16];
        #pragma unroll
        for (int j = 0; j < 16; ++j) {
            unsigned p = (unsigned)__builtin_amdgcn_readlane((int)pk, j);  // 0 for j>=nb
            mm[j] = b2f((unsigned short)(p >> 16));
            vv[j] = *(const unsigned*)(xb + (size_t)(p & 0xFFFFu) * DIM + lane * 2);
        }
        #pragma unroll
        for (int j = 0; j < 16; ++j) {
            acc0 += mm[j] * b2f((unsigned short)(vv[j] & 0xFFFFu));
            acc1 += mm[j] * b2f((unsigned short)(vv[j] >> 16));
        }
    }
    float di = dinv[node];
    float2 xp = *(const float2*)(x + (size_t)node * DIM + lane * 2);
    float2 o;
    o.x = xp.x + acc0 * di;
    o.y = xp.y + acc1 * di;
    *(float2*)(xin + (size_t)node * DIM + lane * 2) = o;
}

// ---------------- GEMM [N,128]x[128,128] + BN + ReLU, split-bf16 MFMA ----------------
__global__ __launch_bounds__(256) void gemm128_bn_relu(const float* __restrict__ xin,
                                                       const float* __restrict__ W,
                                                       const float* __restrict__ bias,
                                                       const float* __restrict__ gam,
                                                       const float* __restrict__ bet,
                                                       const float* __restrict__ rm,
                                                       const float* __restrict__ rv,
                                                       float* __restrict__ out,
                                                       unsigned short* __restrict__ outb) {
    __shared__ unsigned short WTh[128 * 136];   // hi(W^T), +8 pad
    __shared__ unsigned short WTl[128 * 136];   // lo(W^T)
    int tid = threadIdx.x;
    #pragma unroll
    for (int it = 0; it < 16; ++it) {
        int flat = (it * 256 + tid) * 4;       // element in row-major W [k][n]
        int k = flat >> 7;
        int n0 = flat & 127;
        f32x4_t v = *(const f32x4_t*)(W + flat);
        #pragma unroll
        for (int j = 0; j < 4; ++j) {
            unsigned short hi = f2b(v[j]);
            float lo = v[j] - b2f(hi);
            WTh[(n0 + j) * 136 + k] = hi;
            WTl[(n0 + j) * 136 + k] = f2b(lo);
        }
    }
    __syncthreads();

    int wave = tid >> 6, lane = tid & 63;
    int m = lane & 15, quad = lane >> 4;
    int rbase = blockIdx.x * 64 + wave * 16;
    int arow = rbase + m;
    const float* ap = xin + (size_t)(arow < N_NODES ? arow : 0) * DIM;

    us8_t ah[4], al[4];
    #pragma unroll
    for (int kt = 0; kt < 4; ++kt) {
        f32x4_t p0 = *(const f32x4_t*)(ap + kt * 32 + quad * 8);
        f32x4_t p1 = *(const f32x4_t*)(ap + kt * 32 + quad * 8 + 4);
        #pragma unroll
        for (int j = 0; j < 4; ++j) {
            unsigned short h0 = f2b(p0[j]);
            unsigned short h1 = f2b(p1[j]);
            ah[kt][j] = h0;
            ah[kt][4 + j] = h1;
            al[kt][j] = f2b(p0[j] - b2f(h0));
            al[kt][4 + j] = f2b(p1[j] - b2f(h1));
        }
    }

    f32x4_t acc[8] = {};
    #pragma unroll
    for (int kt = 0; kt < 4; ++kt) {
        #pragma unroll
        for (int nt = 0; nt < 8; ++nt) {
            int boff = (nt * 16 + m) * 136 + kt * 32 + quad * 8;
            us8_t bh = *(const us8_t*)(&WTh[boff]);
            us8_t bl = *(const us8_t*)(&WTl[boff]);
            acc[nt] = __builtin_amdgcn_mfma_f32_16x16x32_bf16(
                __builtin_bit_cast(bf16x8_t, ah[kt]),
                __builtin_bit_cast(bf16x8_t, bh), acc[nt], 0, 0, 0);
            acc[nt] = __builtin_amdgcn_mfma_f32_16x16x32_bf16(
                __builtin_bit_cast(bf16x8_t, ah[kt]),
                __builtin_bit_cast(bf16x8_t, bl), acc[nt], 0, 0, 0);
            acc[nt] = __builtin_amdgcn_mfma_f32_16x16x32_bf16(
                __builtin_bit_cast(bf16x8_t, al[kt]),
                __builtin_bit_cast(bf16x8_t, bh), acc[nt], 0, 0, 0);
        }
    }

    #pragma unroll
    for (int nt = 0; nt < 8; ++nt) {
        int j = nt * 16 + m;
        float bj = bias[j];
        float sc = gam[j] * rsqrtf(rv[j] + 1e-5f);
        float sh = bet[j] - rm[j] * sc;
        #pragma unroll
        for (int i = 0; i < 4; ++i) {
            int r = rbase + quad * 4 + i;
            if (r < N_NODES) {
                float z = fmaxf((acc[nt][i] + bj) * sc + sh, 0.f);
                out[(size_t)r * DIM + j] = z;
                outb[(size_t)r * DIM + j] = f2b(z);
            }
        }
    }
}

// ---------------- fused final: h3 = relu(BN((h2+agg)@w2+b2)); out = (h2@wp+bp+h3)*0.5 ----------------
__global__ __launch_bounds__(256) void fused_final(const float* __restrict__ xin2,
                                                   const float* __restrict__ h2,
                                                   const float* __restrict__ w2,
                                                   const float* __restrict__ wp,
                                                   const float* __restrict__ b2,
                                                   const float* __restrict__ g2,
                                                   const float* __restrict__ be2,
                                                   const float* __restrict__ rm2,
                                                   const float* __restrict__ rv2,
                                                   const float* __restrict__ bp,
                                                   float* __restrict__ out) {
    __shared__ unsigned short W2Th[48 * 136];
    __shared__ unsigned short W2Tl[48 * 136];
    __shared__ unsigned short WPTh[48 * 136];
    __shared__ unsigned short WPTl[48 * 136];
    int tid = threadIdx.x;
    #pragma unroll
    for (int it = 0; it < 24; ++it) {
        int flat = it * 256 + tid;             // 48*128 = 6144
        int n = flat >> 7, k = flat & 127;
        float v2 = 0.f, vp = 0.f;
        if (n < NCLS) {
            v2 = w2[k * NCLS + n];
            vp = wp[k * NCLS + n];
        }
        unsigned short h2b = f2b(v2);
        unsigned short hpb = f2b(vp);
        W2Th[n * 136 + k] = h2b;
        W2Tl[n * 136 + k] = f2b(v2 - b2f(h2b));
        WPTh[n * 136 + k] = hpb;
        WPTl[n * 136 + k] = f2b(vp - b2f(hpb));
    }
    __syncthreads();

    int wave = tid >> 6, lane = tid & 63;
    int m = lane & 15, quad = lane >> 4;
    int rbase = blockIdx.x * 64 + wave * 16;
    int arow = rbase + m;
    size_t rowoff = (size_t)(arow < N_NODES ? arow : 0) * DIM;
    const float* ap2 = xin2 + rowoff;
    const float* aph = h2 + rowoff;

    us8_t a2h[4], a2l[4], ahh[4], ahl[4];
    #pragma unroll
    for (int kt = 0; kt < 4; ++kt) {
        f32x4_t p0 = *(const f32x4_t*)(ap2 + kt * 32 + quad * 8);
        f32x4_t p1 = *(const f32x4_t*)(ap2 + kt * 32 + quad * 8 + 4);
        f32x4_t q0 = *(const f32x4_t*)(aph + kt * 32 + quad * 8);
        f32x4_t q1 = *(const f32x4_t*)(aph + kt * 32 + quad * 8 + 4);
        #pragma unroll
        for (int j = 0; j < 4; ++j) {
            unsigned short h0 = f2b(p0[j]), h1 = f2b(p1[j]);
            a2h[kt][j] = h0; a2h[kt][4 + j] = h1;
            a2l[kt][j] = f2b(p0[j] - b2f(h0));
            a2l[kt][4 + j] = f2b(p1[j] - b2f(h1));
            unsigned short g0 = f2b(q0[j]), g1 = f2b(q1[j]);
            ahh[kt][j] = g0; ahh[kt][4 + j] = g1;
            ahl[kt][j] = f2b(q0[j] - b2f(g0));
            ahl[kt][4 + j] = f2b(q1[j] - b2f(g1));
        }
    }

    f32x4_t acc2[3] = {};
    f32x4_t accp[3] = {};
    #pragma unroll
    for (int kt = 0; kt < 4; ++kt) {
        #pragma unroll
        for (int nt = 0; nt < 3; ++nt) {
            int boff = (nt * 16 + m) * 136 + kt * 32 + quad * 8;
            us8_t b2hv = *(const us8_t*)(&W2Th[boff]);
            us8_t b2lv = *(const us8_t*)(&W2Tl[boff]);
            us8_t bphv = *(const us8_t*)(&WPTh[boff]);
            us8_t bplv = *(const us8_t*)(&WPTl[boff]);
            acc2[nt] = __builtin_amdgcn_mfma_f32_16x16x32_bf16(
                __builtin_bit_cast(bf16x8_t, a2h[kt]),
                __builtin_bit_cast(bf16x8_t, b2hv), acc2[nt], 0, 0, 0);
            acc2[nt] = __builtin_amdgcn_mfma_f32_16x16x32_bf16(
                __builtin_bit_cast(bf16x8_t, a2h[kt]),
                __builtin_bit_cast(bf16x8_t, b2lv), acc2[nt], 0, 0, 0);
            acc2[nt] = __builtin_amdgcn_mfma_f32_16x16x32_bf16(
                __builtin_bit_cast(bf16x8_t, a2l[kt]),
                __builtin_bit_cast(bf16x8_t, b2hv), acc2[nt], 0, 0, 0);
            accp[nt] = __builtin_amdgcn_mfma_f32_16x16x32_bf16(
                __builtin_bit_cast(bf16x8_t, ahh[kt]),
                __builtin_bit_cast(bf16x8_t, bphv), accp[nt], 0, 0, 0);
            accp[nt] = __builtin_amdgcn_mfma_f32_16x16x32_bf16(
                __builtin_bit_cast(bf16x8_t, ahh[kt]),
                __builtin_bit_cast(bf16x8_t, bplv), accp[nt], 0, 0, 0);
            accp[nt] = __builtin_amdgcn_mfma_f32_16x16x32_bf16(
                __builtin_bit_cast(bf16x8_t, ahl[kt]),
                __builtin_bit_cast(bf16x8_t, bphv), accp[nt], 0, 0, 0);
        }
    }

    #pragma unroll
    for (int nt = 0; nt < 3; ++nt) {
        int j = nt * 16 + m;
        int jc = (j < NCLS) ? j : (NCLS - 1);
        float b2j = b2[jc];
        float sc = g2[jc] * rsqrtf(rv2[jc] + 1e-5f);
        float sh = be2[jc] - rm2[jc] * sc;
        float bpj = bp[jc];
        #pragma unroll
        for (int i = 0; i < 4; ++i) {
            int r = rbase + quad * 4 + i;
            if (r < N_NODES && j < NCLS) {
                float z = fmaxf((acc2[nt][i] + b2j) * sc + sh, 0.f);
                float p = accp[nt][i] + bpj;
                out[(size_t)r * NCLS + j] = (p + z) * 0.5f;
            }
        }
    }
}

extern "C" void kernel_launch(void* const* d_in, const int* in_sizes, int n_in,
                              void* d_out, int out_size, void* d_ws, size_t ws_size,
                              hipStream_t stream) {
    const float* h    = (const float*)d_in[0];
    const int* esrc   = (const int*)d_in[1];
    const int* edst   = (const int*)d_in[2];
    const float* mask = (const float*)d_in[3];
    const float* w0   = (const float*)d_in[4];
    const float* b0   = (const float*)d_in[5];
    const float* g0   = (const float*)d_in[6];
    const float* be0  = (const float*)d_in[7];
    const float* rm0  = (const float*)d_in[8];
    const float* rv0  = (const float*)d_in[9];
    const float* w1   = (const float*)d_in[10];
    const float* b1   = (const float*)d_in[11];
    const float* g1   = (const float*)d_in[12];
    const float* be1  = (const float*)d_in[13];
    const float* rm1  = (const float*)d_in[14];
    const float* rv1  = (const float*)d_in[15];
    const float* w2   = (const float*)d_in[16];
    const float* b2   = (const float*)d_in[17];
    const float* g2   = (const float*)d_in[18];
    const float* be2  = (const float*)d_in[19];
    const float* rm2  = (const float*)d_in[20];
    const float* rv2  = (const float*)d_in[21];
    const float* wp   = (const float*)d_in[22];
    const float* bp   = (const float*)d_in[23];

    char* ws = (char*)d_ws;
    size_t off = 0;
    auto alloc = [&](size_t bytes) {
        char* p = ws + off;
        off = (off + bytes + 255) & ~(size_t)255;
        return p;
    };
    int* rs       = (int*)alloc(N_PAD * 4);
    int* deg      = (int*)alloc(N_PAD * 4);
    float* dinv   = (float*)alloc(N_PAD * 4);
    int* partial  = (int*)alloc(128 * 4);
    int* blk_off  = (int*)alloc(128 * 4);
    unsigned* degp = (unsigned*)alloc(2 * WHALF * 4);
    unsigned* csr = (unsigned*)alloc((size_t)N_EDGES * 4);
    float* xin    = (float*)alloc((size_t)N_NODES * DIM * 4);
    float* hb     = (float*)alloc((size_t)N_NODES * DIM * 4);
    unsigned short* xb16 = (unsigned short*)alloc((size_t)N_NODES * DIM * 2);
    unsigned short* hb16 = (unsigned short*)alloc((size_t)N_NODES * DIM * 2);
    // cnt (12.85 MB) aliases xin (25.6 MB): fully consumed by fill2 before agg writes xin
    unsigned* cnt = (unsigned*)xin;

    const int AB = (N_NODES + 3) / 4;
    const int GB = (N_NODES + 63) / 64;

    to_bf16<<<3125, 256, 0, stream>>>(h, xb16);
    chunk_count<<<NCHUNK, 256, 0, stream>>>(edst, cnt);
    cscan<<<SCAN_B, 256, 0, stream>>>(cnt, degp, partial);
    scan_blocks<<<1, 128, 0, stream>>>(partial, blk_off);
    scan_final<<<SCAN_B, 256, 0, stream>>>(degp, blk_off, rs, deg, dinv);
    fill2<<<NCHUNK, 256, 0, stream>>>(esrc, edst, mask, cnt, rs, csr);

    // layer 0
    agg_kernel<<<AB, 256, 0, stream>>>(xb16, h, xin, rs, deg, dinv, csr);
    gemm128_bn_relu<<<GB, 256, 0, stream>>>(xin, w0, b0, g0, be0, rm0, rv0, hb, hb16);
    // layer 1
    agg_kernel<<<AB, 256, 0, stream>>>(hb16, hb, xin, rs, deg, dinv, csr);
    gemm128_bn_relu<<<GB, 256, 0, stream>>>(xin, w1, b1, g1, be1, rm1, rv1, hb, hb16);
    // layer 2 + predict, fused
    agg_kernel<<<AB, 256, 0, stream>>>(hb16, hb, xin, rs, deg, dinv, csr);
    fused_final<<<GB, 256, 0, stream>>>(xin, hb, w2, wp, b2, g2, be2, rm2, rv2, bp,
                                        (float*)d_out);
}

// Round 8
// 407.398 us; speedup vs baseline: 1.0774x; 1.0201x over previous
//
#include <hip/hip_runtime.h>

#define N_NODES 50000
#define N_EDGES 800000
#define DIM 128
#define NCLS 40

// chunked CSR build
#define NCHUNK 128
#define CE 6250            // NCHUNK*CE == N_EDGES exactly
#define HALF_N 25088       // nodes per half (2*WHALF)
#define WHALF 12544        // packed u32 words per half (= 49*256)
#define SCAN_B 98          // cscan/scan_final blocks (2 halves * 49)
#define N_PAD 50432        // >= 2*HALF_N padded node arrays

typedef __bf16 bf16x8_t __attribute__((ext_vector_type(8)));
typedef unsigned short us8_t __attribute__((ext_vector_type(8)));
typedef float f32x4_t __attribute__((ext_vector_type(4)));

static __device__ __forceinline__ float b2f(unsigned short h) {
    unsigned u = ((unsigned)h) << 16;
    return __builtin_bit_cast(float, u);
}
static __device__ __forceinline__ unsigned short f2b(float f) {
    unsigned u = __builtin_bit_cast(unsigned, f);
    u += 0x7FFFu + ((u >> 16) & 1u);   // RNE; values finite O(1)
    return (unsigned short)(u >> 16);
}

// ---------------- f32 -> bf16 shadow of h ----------------
__global__ __launch_bounds__(256) void to_bf16(const float* __restrict__ in,
                                               unsigned short* __restrict__ out) {
    size_t e0 = ((size_t)blockIdx.x * 256 + threadIdx.x) * 8;   // 3125*256*8 = 6.4M exact
    f32x4_t v0 = *(const f32x4_t*)(in + e0);
    f32x4_t v1 = *(const f32x4_t*)(in + e0 + 4);
    us8_t o;
    #pragma unroll
    for (int j = 0; j < 4; ++j) { o[j] = f2b(v0[j]); o[4 + j] = f2b(v1[j]); }
    *(us8_t*)(out + e0) = o;
}

// ---------------- per-chunk per-node edge counts (LDS atomics) ----------------
__global__ __launch_bounds__(256) void chunk_count(const int* __restrict__ dst,
                                                   unsigned* __restrict__ cnt) {
    __shared__ unsigned lds[WHALF];   // 50 KB
    int c = blockIdx.x, tid = threadIdx.x;
    for (int h = 0; h < 2; ++h) {
        for (int w = tid; w < WHALF; w += 256) lds[w] = 0;
        __syncthreads();
        int base = c * CE;
        for (int k = tid; k < CE; k += 256) {
            int local = dst[base + k] - h * HALF_N;
            if (local >= 0 && local < HALF_N)
                atomicAdd(&lds[local >> 1], 1u << ((local & 1) * 16));
        }
        __syncthreads();
        unsigned* out = cnt + ((size_t)(h * NCHUNK + c)) * WHALF;
        for (int w = tid; w < WHALF; w += 256) out[w] = lds[w];
        __syncthreads();
    }
}

// ---------------- scan over chunk axis ----------------
__global__ __launch_bounds__(256) void cscan(unsigned* __restrict__ cnt,
                                             unsigned* __restrict__ degp,
                                             int* __restrict__ partial) {
    __shared__ int lds[256];
    int b = blockIdx.x;
    int h = b / 49;
    int w = (b % 49) * 256 + threadIdx.x;
    unsigned acc = 0;
    for (int c = 0; c < NCHUNK; ++c) {
        size_t idx = ((size_t)(h * NCHUNK + c)) * WHALF + w;
        unsigned v = cnt[idx];
        cnt[idx] = acc;          // exclusive prefix (packed halves)
        acc += v;
    }
    degp[h * WHALF + w] = acc;
    lds[threadIdx.x] = (int)(acc & 0xFFFFu) + (int)(acc >> 16);
    __syncthreads();
    #pragma unroll
    for (int off = 128; off > 0; off >>= 1) {
        if (threadIdx.x < off) lds[threadIdx.x] += lds[threadIdx.x + off];
        __syncthreads();
    }
    if (threadIdx.x == 0) partial[b] = lds[0];
}

__global__ __launch_bounds__(128) void scan_blocks(const int* __restrict__ partial,
                                                   int* __restrict__ blk_off) {
    __shared__ int lds[128];
    int tid = threadIdx.x;
    lds[tid] = (tid < SCAN_B) ? partial[tid] : 0;
    __syncthreads();
    #pragma unroll
    for (int off = 1; off < 128; off <<= 1) {
        int v = lds[tid];
        int add = (tid >= off) ? lds[tid - off] : 0;
        __syncthreads();
        lds[tid] = v + add;
        __syncthreads();
    }
    if (tid < SCAN_B) blk_off[tid] = (tid == 0) ? 0 : lds[tid - 1];
}

// ---------------- final node-axis scan: rs / deg / dinv ----------------
__global__ __launch_bounds__(256) void scan_final(const unsigned* __restrict__ degp,
                                                  const int* __restrict__ blk_off,
                                                  int* __restrict__ rs,
                                                  int* __restrict__ deg,
                                                  float* __restrict__ dinv) {
    __shared__ int lds[256];
    int b = blockIdx.x;
    int h = b / 49;
    int tid = threadIdx.x;
    int w = (b % 49) * 256 + tid;
    unsigned dp = degp[h * WHALF + w];
    int lo = (int)(dp & 0xFFFFu), hi = (int)(dp >> 16);
    int s = lo + hi;
    lds[tid] = s;
    __syncthreads();
    #pragma unroll
    for (int off = 1; off < 256; off <<= 1) {
        int v = lds[tid];
        int add = (tid >= off) ? lds[tid - off] : 0;
        __syncthreads();
        lds[tid] = v + add;
        __syncthreads();
    }
    int excl = blk_off[b] + lds[tid] - s;
    int n0 = h * HALF_N + 2 * w;
    rs[n0] = excl;
    rs[n0 + 1] = excl + lo;
    deg[n0] = lo;
    deg[n0 + 1] = hi;
    dinv[n0] = (lo > 0) ? (1.0f / (float)lo) : 0.0f;
    dinv[n0 + 1] = (hi > 0) ? (1.0f / (float)hi) : 0.0f;
}

// ---------------- CSR fill: rank via LDS returning atomics ----------------
__global__ __launch_bounds__(256) void fill2(const int* __restrict__ src,
                                             const int* __restrict__ dst,
                                             const float* __restrict__ mask,
                                             const unsigned* __restrict__ cnt,
                                             const int* __restrict__ rs,
                                             unsigned* __restrict__ csr) {
    __shared__ unsigned cur[WHALF];   // 50 KB
    int c = blockIdx.x, tid = threadIdx.x;
    for (int h = 0; h < 2; ++h) {
        const unsigned* off = cnt + ((size_t)(h * NCHUNK + c)) * WHALF;
        for (int w = tid; w < WHALF; w += 256) cur[w] = off[w];
        __syncthreads();
        int base = c * CE;
        for (int k = tid; k < CE; k += 256) {
            int e = base + k;
            int d = dst[e];
            int local = d - h * HALF_N;
            if (local >= 0 && local < HALF_N) {
                unsigned sm = (unsigned)src[e] | ((unsigned)f2b(mask[e]) << 16);
                int sh = (local & 1) * 16;
                unsigned old = atomicAdd(&cur[local >> 1], 1u << sh);
                int rank = (int)((old >> sh) & 0xFFFFu);
                csr[rs[d] + rank] = sm;
            }
        }
        __syncthreads();
    }
}

// ---------------- mean aggregation: bf16 gather + f32 residual ----------------
__global__ __launch_bounds__(256) void agg_kernel(const unsigned short* __restrict__ xb,
                                                  const float* __restrict__ x,
                                                  float* __restrict__ xin,
                                                  const int* __restrict__ rs,
                                                  const int* __restrict__ deg,
                                                  const float* __restrict__ dinv,
                                                  const unsigned* __restrict__ csr) {
    int lane = threadIdx.x & 63;
    int node = blockIdx.x * 4 + (threadIdx.x >> 6);
    if (node >= N_NODES) return;
    int cnt = deg[node];
    int start = rs[node];
    float acc0 = 0.f, acc1 = 0.f;
    for (int base = 0; base < cnt; base += 16) {
        int nb = cnt - base;
        if (nb > 16) nb = 16;
        unsigned pk = 0;
        if (lane < nb) pk = csr[start + base + lane];
        unsigned vv[16];
        float mm[16];
        #pragma unroll
        for (int j = 0; j < 16; ++j) {
            unsigned p = (unsigned)__builtin_amdgcn_readlane((int)pk, j);  // 0 for j>=nb
            mm[j] = b2f((unsigned short)(p >> 16));
            vv[j] = *(const unsigned*)(xb + (size_t)(p & 0xFFFFu) * DIM + lane * 2);
        }
        #pragma unroll
        for (int j = 0; j < 16; ++j) {
            acc0 += mm[j] * b2f((unsigned short)(vv[j] & 0xFFFFu));
            acc1 += mm[j] * b2f((unsigned short)(vv[j] >> 16));
        }
    }
    float di = dinv[node];
    float2 xp = *(const float2*)(x + (size_t)node * DIM + lane * 2);
    float2 o;
    o.x = xp.x + acc0 * di;
    o.y = xp.y + acc1 * di;
    *(float2*)(xin + (size_t)node * DIM + lane * 2) = o;
}

// ---------------- GEMM [N,128]x[128,128] + BN + ReLU, split-bf16 MFMA ----------------
// LDS in MFMA fragment order: chunk (nt,kt,quad,m) at ((nt*4+kt)*64 + quad*16 + m)*8
// -> wave's 64 lanes read 64 consecutive 16B chunks: conflict-free.
__global__ __launch_bounds__(256) void gemm128_bn_relu(const float* __restrict__ xin,
                                                       const float* __restrict__ W,
                                                       const float* __restrict__ bias,
                                                       const float* __restrict__ gam,
                                                       const float* __restrict__ bet,
                                                       const float* __restrict__ rm,
                                                       const float* __restrict__ rv,
                                                       float* __restrict__ out,
                                                       unsigned short* __restrict__ outb) {
    __shared__ unsigned short WTh[128 * 128];   // 32 KB, fragment order
    __shared__ unsigned short WTl[128 * 128];
    int tid = threadIdx.x;
    #pragma unroll
    for (int it = 0; it < 16; ++it) {
        int flat = (it * 256 + tid) * 4;       // W row-major [k][n], 4 consecutive n
        int k = flat >> 7;
        int n0 = flat & 127;
        int kt = k >> 5, quad = (k >> 3) & 3, j = k & 7;
        f32x4_t v = *(const f32x4_t*)(W + flat);
        #pragma unroll
        for (int jj = 0; jj < 4; ++jj) {
            int n = n0 + jj;
            int nt = n >> 4, m = n & 15;
            int off = ((nt * 4 + kt) * 64 + quad * 16 + m) * 8 + j;
            unsigned short hi = f2b(v[jj]);
            WTh[off] = hi;
            WTl[off] = f2b(v[jj] - b2f(hi));
        }
    }
    __syncthreads();

    int wave = tid >> 6, lane = tid & 63;
    int m = lane & 15, quad = lane >> 4;
    int rbase = blockIdx.x * 64 + wave * 16;
    int arow = rbase + m;
    const float* ap = xin + (size_t)(arow < N_NODES ? arow : 0) * DIM;

    us8_t ah[4], al[4];
    #pragma unroll
    for (int kt = 0; kt < 4; ++kt) {
        f32x4_t p0 = *(const f32x4_t*)(ap + kt * 32 + quad * 8);
        f32x4_t p1 = *(const f32x4_t*)(ap + kt * 32 + quad * 8 + 4);
        #pragma unroll
        for (int j = 0; j < 4; ++j) {
            unsigned short h0 = f2b(p0[j]);
            unsigned short h1 = f2b(p1[j]);
            ah[kt][j] = h0;
            ah[kt][4 + j] = h1;
            al[kt][j] = f2b(p0[j] - b2f(h0));
            al[kt][4 + j] = f2b(p1[j] - b2f(h1));
        }
    }

    f32x4_t acc[8] = {};
    #pragma unroll
    for (int kt = 0; kt < 4; ++kt) {
        #pragma unroll
        for (int nt = 0; nt < 8; ++nt) {
            int boff = ((nt * 4 + kt) * 64 + quad * 16 + m) * 8;
            us8_t bh = *(const us8_t*)(&WTh[boff]);
            us8_t bl = *(const us8_t*)(&WTl[boff]);
            acc[nt] = __builtin_amdgcn_mfma_f32_16x16x32_bf16(
                __builtin_bit_cast(bf16x8_t, ah[kt]),
                __builtin_bit_cast(bf16x8_t, bh), acc[nt], 0, 0, 0);
            acc[nt] = __builtin_amdgcn_mfma_f32_16x16x32_bf16(
                __builtin_bit_cast(bf16x8_t, ah[kt]),
                __builtin_bit_cast(bf16x8_t, bl), acc[nt], 0, 0, 0);
            acc[nt] = __builtin_amdgcn_mfma_f32_16x16x32_bf16(
                __builtin_bit_cast(bf16x8_t, al[kt]),
                __builtin_bit_cast(bf16x8_t, bh), acc[nt], 0, 0, 0);
        }
    }

    #pragma unroll
    for (int nt = 0; nt < 8; ++nt) {
        int j = nt * 16 + m;
        float bj = bias[j];
        float sc = gam[j] * rsqrtf(rv[j] + 1e-5f);
        float sh = bet[j] - rm[j] * sc;
        #pragma unroll
        for (int i = 0; i < 4; ++i) {
            int r = rbase + quad * 4 + i;
            if (r < N_NODES) {
                float z = fmaxf((acc[nt][i] + bj) * sc + sh, 0.f);
                out[(size_t)r * DIM + j] = z;
                outb[(size_t)r * DIM + j] = f2b(z);
            }
        }
    }
}

// ---------------- fused final: h3 = relu(BN((h2+agg)@w2+b2)); out = (h2@wp+bp+h3)*0.5 ----------------
__global__ __launch_bounds__(256) void fused_final(const float* __restrict__ xin2,
                                                   const float* __restrict__ h2,
                                                   const float* __restrict__ w2,
                                                   const float* __restrict__ wp,
                                                   const float* __restrict__ b2,
                                                   const float* __restrict__ g2,
                                                   const float* __restrict__ be2,
                                                   const float* __restrict__ rm2,
                                                   const float* __restrict__ rv2,
                                                   const float* __restrict__ bp,
                                                   float* __restrict__ out) {
    __shared__ unsigned short W2Th[48 * 128];   // fragment order, 12 KB each
    __shared__ unsigned short W2Tl[48 * 128];
    __shared__ unsigned short WPTh[48 * 128];
    __shared__ unsigned short WPTl[48 * 128];
    int tid = threadIdx.x;
    #pragma unroll
    for (int it = 0; it < 24; ++it) {
        int flat = it * 256 + tid;             // 48*128 = 6144
        int n = flat >> 7, k = flat & 127;
        float v2 = 0.f, vp = 0.f;
        if (n < NCLS) {
            v2 = w2[k * NCLS + n];
            vp = wp[k * NCLS + n];
        }
        int nt = n >> 4, m = n & 15, kt = k >> 5, quad = (k >> 3) & 3, j = k & 7;
        int off = ((nt * 4 + kt) * 64 + quad * 16 + m) * 8 + j;
        unsigned short h2b = f2b(v2);
        unsigned short hpb = f2b(vp);
        W2Th[off] = h2b;
        W2Tl[off] = f2b(v2 - b2f(h2b));
        WPTh[off] = hpb;
        WPTl[off] = f2b(vp - b2f(hpb));
    }
    __syncthreads();

    int wave = tid >> 6, lane = tid & 63;
    int m = lane & 15, quad = lane >> 4;
    int rbase = blockIdx.x * 64 + wave * 16;
    int arow = rbase + m;
    size_t rowoff = (size_t)(arow < N_NODES ? arow : 0) * DIM;
    const float* ap2 = xin2 + rowoff;
    const float* aph = h2 + rowoff;

    us8_t a2h[4], a2l[4], ahh[4], ahl[4];
    #pragma unroll
    for (int kt = 0; kt < 4; ++kt) {
        f32x4_t p0 = *(const f32x4_t*)(ap2 + kt * 32 + quad * 8);
        f32x4_t p1 = *(const f32x4_t*)(ap2 + kt * 32 + quad * 8 + 4);
        f32x4_t q0 = *(const f32x4_t*)(aph + kt * 32 + quad * 8);
        f32x4_t q1 = *(const f32x4_t*)(aph + kt * 32 + quad * 8 + 4);
        #pragma unroll
        for (int j = 0; j < 4; ++j) {
            unsigned short h0 = f2b(p0[j]), h1 = f2b(p1[j]);
            a2h[kt][j] = h0; a2h[kt][4 + j] = h1;
            a2l[kt][j] = f2b(p0[j] - b2f(h0));
            a2l[kt][4 + j] = f2b(p1[j] - b2f(h1));
            unsigned short g0 = f2b(q0[j]), g1 = f2b(q1[j]);
            ahh[kt][j] = g0; ahh[kt][4 + j] = g1;
            ahl[kt][j] = f2b(q0[j] - b2f(g0));
            ahl[kt][4 + j] = f2b(q1[j] - b2f(g1));
        }
    }

    f32x4_t acc2[3] = {};
    f32x4_t accp[3] = {};
    #pragma unroll
    for (int kt = 0; kt < 4; ++kt) {
        #pragma unroll
        for (int nt = 0; nt < 3; ++nt) {
            int boff = ((nt * 4 + kt) * 64 + quad * 16 + m) * 8;
            us8_t b2hv = *(const us8_t*)(&W2Th[boff]);
            us8_t b2lv = *(const us8_t*)(&W2Tl[boff]);
            us8_t bphv = *(const us8_t*)(&WPTh[boff]);
            us8_t bplv = *(const us8_t*)(&WPTl[boff]);
            acc2[nt] = __builtin_amdgcn_mfma_f32_16x16x32_bf16(
                __builtin_bit_cast(bf16x8_t, a2h[kt]),
                __builtin_bit_cast(bf16x8_t, b2hv), acc2[nt], 0, 0, 0);
            acc2[nt] = __builtin_amdgcn_mfma_f32_16x16x32_bf16(
                __builtin_bit_cast(bf16x8_t, a2h[kt]),
                __builtin_bit_cast(bf16x8_t, b2lv), acc2[nt], 0, 0, 0);
            acc2[nt] = __builtin_amdgcn_mfma_f32_16x16x32_bf16(
                __builtin_bit_cast(bf16x8_t, a2l[kt]),
                __builtin_bit_cast(bf16x8_t, b2hv), acc2[nt], 0, 0, 0);
            accp[nt] = __builtin_amdgcn_mfma_f32_16x16x32_bf16(
                __builtin_bit_cast(bf16x8_t, ahh[kt]),
                __builtin_bit_cast(bf16x8_t, bphv), accp[nt], 0, 0, 0);
            accp[nt] = __builtin_amdgcn_mfma_f32_16x16x32_bf16(
                __builtin_bit_cast(bf16x8_t, ahh[kt]),
                __builtin_bit_cast(bf16x8_t, bplv), accp[nt], 0, 0, 0);
            accp[nt] = __builtin_amdgcn_mfma_f32_16x16x32_bf16(
                __builtin_bit_cast(bf16x8_t, ahl[kt]),
                __builtin_bit_cast(bf16x8_t, bphv), accp[nt], 0, 0, 0);
        }
    }

    #pragma unroll
    for (int nt = 0; nt < 3; ++nt) {
        int j = nt * 16 + m;
        int jc = (j < NCLS) ? j : (NCLS - 1);
        float b2j = b2[jc];
        float sc = g2[jc] * rsqrtf(rv2[jc] + 1e-5f);
        float sh = be2[jc] - rm2[jc] * sc;
        float bpj = bp[jc];
        #pragma unroll
        for (int i = 0; i < 4; ++i) {
            int r = rbase + quad * 4 + i;
            if (r < N_NODES && j < NCLS) {
                float z = fmaxf((acc2[nt][i] + b2j) * sc + sh, 0.f);
                float p = accp[nt][i] + bpj;
                out[(size_t)r * NCLS + j] = (p + z) * 0.5f;
            }
        }
    }
}

extern "C" void kernel_launch(void* const* d_in, const int* in_sizes, int n_in,
                              void* d_out, int out_size, void* d_ws, size_t ws_size,
                              hipStream_t stream) {
    const float* h    = (const float*)d_in[0];
    const int* esrc   = (const int*)d_in[1];
    const int* edst   = (const int*)d_in[2];
    const float* mask = (const float*)d_in[3];
    const float* w0   = (const float*)d_in[4];
    const float* b0   = (const float*)d_in[5];
    const float* g0   = (const float*)d_in[6];
    const float* be0  = (const float*)d_in[7];
    const float* rm0  = (const float*)d_in[8];
    const float* rv0  = (const float*)d_in[9];
    const float* w1   = (const float*)d_in[10];
    const float* b1   = (const float*)d_in[11];
    const float* g1   = (const float*)d_in[12];
    const float* be1  = (const float*)d_in[13];
    const float* rm1  = (const float*)d_in[14];
    const float* rv1  = (const float*)d_in[15];
    const float* w2   = (const float*)d_in[16];
    const float* b2   = (const float*)d_in[17];
    const float* g2   = (const float*)d_in[18];
    const float* be2  = (const float*)d_in[19];
    const float* rm2  = (const float*)d_in[20];
    const float* rv2  = (const float*)d_in[21];
    const float* wp   = (const float*)d_in[22];
    const float* bp   = (const float*)d_in[23];

    char* ws = (char*)d_ws;
    size_t off = 0;
    auto alloc = [&](size_t bytes) {
        char* p = ws + off;
        off = (off + bytes + 255) & ~(size_t)255;
        return p;
    };
    int* rs       = (int*)alloc(N_PAD * 4);
    int* deg      = (int*)alloc(N_PAD * 4);
    float* dinv   = (float*)alloc(N_PAD * 4);
    int* partial  = (int*)alloc(128 * 4);
    int* blk_off  = (int*)alloc(128 * 4);
    unsigned* degp = (unsigned*)alloc(2 * WHALF * 4);
    unsigned* csr = (unsigned*)alloc((size_t)N_EDGES * 4);
    float* xin    = (float*)alloc((size_t)N_NODES * DIM * 4);
    float* hb     = (float*)alloc((size_t)N_NODES * DIM * 4);
    unsigned short* xb16 = (unsigned short*)alloc((size_t)N_NODES * DIM * 2);
    unsigned short* hb16 = (unsigned short*)alloc((size_t)N_NODES * DIM * 2);
    // cnt (12.85 MB) aliases xin (25.6 MB): fully consumed by fill2 before agg writes xin
    unsigned* cnt = (unsigned*)xin;

    const int AB = (N_NODES + 3) / 4;
    const int GB = (N_NODES + 63) / 64;

    to_bf16<<<3125, 256, 0, stream>>>(h, xb16);
    chunk_count<<<NCHUNK, 256, 0, stream>>>(edst, cnt);
    cscan<<<SCAN_B, 256, 0, stream>>>(cnt, degp, partial);
    scan_blocks<<<1, 128, 0, stream>>>(partial, blk_off);
    scan_final<<<SCAN_B, 256, 0, stream>>>(degp, blk_off, rs, deg, dinv);
    fill2<<<NCHUNK, 256, 0, stream>>>(esrc, edst, mask, cnt, rs, csr);

    // layer 0
    agg_kernel<<<AB, 256, 0, stream>>>(xb16, h, xin, rs, deg, dinv, csr);
    gemm128_bn_relu<<<GB, 256, 0, stream>>>(xin, w0, b0, g0, be0, rm0, rv0, hb, hb16);
    // layer 1
    agg_kernel<<<AB, 256, 0, stream>>>(hb16, hb, xin, rs, deg, dinv, csr);
    gemm128_bn_relu<<<GB, 256, 0, stream>>>(xin, w1, b1, g1, be1, rm1, rv1, hb, hb16);
    // layer 2 + predict, fused
    agg_kernel<<<AB, 256, 0, stream>>>(hb16, hb, xin, rs, deg, dinv, csr);
    fused_final<<<GB, 256, 0, stream>>>(xin, hb, w2, wp, b2, g2, be2, rm2, rv2, bp,
                                        (float*)d_out);
}

// Round 9
// 327.370 us; speedup vs baseline: 1.3408x; 1.2445x over previous
//
#include <hip/hip_runtime.h>

#define N_NODES 50000
#define N_EDGES 800000
#define DIM 128
#define NCLS 40

// chunked CSR build
#define NCHUNK 128
#define CE 6250            // NCHUNK*CE == N_EDGES exactly
#define HALF_N 25088       // nodes per half (2*WHALF)
#define WHALF 12544        // packed u32 words per half (= 49*256)
#define SCAN_B 98          // cscan/scan_final blocks (2 halves * 49)
#define N_PAD 50432        // >= 2*HALF_N padded node arrays

typedef __bf16 bf16x8_t __attribute__((ext_vector_type(8)));
typedef unsigned short us8_t __attribute__((ext_vector_type(8)));
typedef float f32x4_t __attribute__((ext_vector_type(4)));

static __device__ __forceinline__ float b2f(unsigned short h) {
    unsigned u = ((unsigned)h) << 16;
    return __builtin_bit_cast(float, u);
}
static __device__ __forceinline__ unsigned short f2b(float f) {
    unsigned u = __builtin_bit_cast(unsigned, f);
    u += 0x7FFFu + ((u >> 16) & 1u);   // RNE; values finite O(1)
    return (unsigned short)(u >> 16);
}

// ---------------- f32 -> bf16 shadow of h ----------------
__global__ __launch_bounds__(256) void to_bf16(const float* __restrict__ in,
                                               unsigned short* __restrict__ out) {
    size_t e0 = ((size_t)blockIdx.x * 256 + threadIdx.x) * 8;   // 3125*256*8 = 6.4M exact
    f32x4_t v0 = *(const f32x4_t*)(in + e0);
    f32x4_t v1 = *(const f32x4_t*)(in + e0 + 4);
    us8_t o;
    #pragma unroll
    for (int j = 0; j < 4; ++j) { o[j] = f2b(v0[j]); o[4 + j] = f2b(v1[j]); }
    *(us8_t*)(out + e0) = o;
}

// ---------------- one-time weight repack into MFMA fragment order (global) ----------------
// frag offset for (k,n): nt=n>>4,m=n&15,kt=k>>5,quad=(k>>3)&3,j=k&7
//   off = ((nt*4+kt)*64 + quad*16 + m)*8 + j   -> lane L=quad*16+m reads chunk L contiguous
__global__ __launch_bounds__(256) void repack_w(const float* __restrict__ w0,
                                                const float* __restrict__ w1,
                                                const float* __restrict__ w2,
                                                const float* __restrict__ wp,
                                                unsigned short* __restrict__ f0h,
                                                unsigned short* __restrict__ f0l,
                                                unsigned short* __restrict__ f1h,
                                                unsigned short* __restrict__ f1l,
                                                unsigned short* __restrict__ f2h,
                                                unsigned short* __restrict__ f2l,
                                                unsigned short* __restrict__ fph,
                                                unsigned short* __restrict__ fpl) {
    int t = blockIdx.x * 256 + threadIdx.x;
    const float* src;
    unsigned short *dh, *dl;
    int idx, ncols;
    if (t < 16384)      { src = w0; dh = f0h; dl = f0l; idx = t;         ncols = 128; }
    else if (t < 32768) { src = w1; dh = f1h; dl = f1l; idx = t - 16384; ncols = 128; }
    else if (t < 38912) { src = w2; dh = f2h; dl = f2l; idx = t - 32768; ncols = 48; }
    else if (t < 45056) { src = wp; dh = fph; dl = fpl; idx = t - 38912; ncols = 48; }
    else return;
    int k = idx / ncols, n = idx - k * ncols;
    float v;
    if (ncols == 128) v = src[k * 128 + n];
    else              v = (n < NCLS) ? src[k * NCLS + n] : 0.f;
    int nt = n >> 4, m = n & 15, kt = k >> 5, quad = (k >> 3) & 3, j = k & 7;
    int off = ((nt * 4 + kt) * 64 + quad * 16 + m) * 8 + j;
    unsigned short hi = f2b(v);
    dh[off] = hi;
    dl[off] = f2b(v - b2f(hi));
}

// ---------------- per-chunk per-node edge counts (LDS atomics); blockIdx.y = half ----------------
__global__ __launch_bounds__(256) void chunk_count(const int* __restrict__ dst,
                                                   unsigned* __restrict__ cnt) {
    __shared__ unsigned lds[WHALF];   // 50 KB
    int c = blockIdx.x, h = blockIdx.y, tid = threadIdx.x;
    for (int w = tid; w < WHALF; w += 256) lds[w] = 0;
    __syncthreads();
    int base = c * CE;
    for (int k = tid; k < CE; k += 256) {
        int local = dst[base + k] - h * HALF_N;
        if (local >= 0 && local < HALF_N)
            atomicAdd(&lds[local >> 1], 1u << ((local & 1) * 16));
    }
    __syncthreads();
    unsigned* out = cnt + ((size_t)(h * NCHUNK + c)) * WHALF;
    for (int w = tid; w < WHALF; w += 256) out[w] = lds[w];
}

// ---------------- scan over chunk axis ----------------
__global__ __launch_bounds__(256) void cscan(unsigned* __restrict__ cnt,
                                             unsigned* __restrict__ degp,
                                             int* __restrict__ partial) {
    __shared__ int lds[256];
    int b = blockIdx.x;
    int h = b / 49;
    int w = (b % 49) * 256 + threadIdx.x;
    unsigned acc = 0;
    for (int c = 0; c < NCHUNK; ++c) {
        size_t idx = ((size_t)(h * NCHUNK + c)) * WHALF + w;
        unsigned v = cnt[idx];
        cnt[idx] = acc;          // exclusive prefix (packed halves)
        acc += v;
    }
    degp[h * WHALF + w] = acc;
    lds[threadIdx.x] = (int)(acc & 0xFFFFu) + (int)(acc >> 16);
    __syncthreads();
    #pragma unroll
    for (int off = 128; off > 0; off >>= 1) {
        if (threadIdx.x < off) lds[threadIdx.x] += lds[threadIdx.x + off];
        __syncthreads();
    }
    if (threadIdx.x == 0) partial[b] = lds[0];
}

__global__ __launch_bounds__(128) void scan_blocks(const int* __restrict__ partial,
                                                   int* __restrict__ blk_off) {
    __shared__ int lds[128];
    int tid = threadIdx.x;
    lds[tid] = (tid < SCAN_B) ? partial[tid] : 0;
    __syncthreads();
    #pragma unroll
    for (int off = 1; off < 128; off <<= 1) {
        int v = lds[tid];
        int add = (tid >= off) ? lds[tid - off] : 0;
        __syncthreads();
        lds[tid] = v + add;
        __syncthreads();
    }
    if (tid < SCAN_B) blk_off[tid] = (tid == 0) ? 0 : lds[tid - 1];
}

// ---------------- final node-axis scan: rs / deg / dinv ----------------
__global__ __launch_bounds__(256) void scan_final(const unsigned* __restrict__ degp,
                                                  const int* __restrict__ blk_off,
                                                  int* __restrict__ rs,
                                                  int* __restrict__ deg,
                                                  float* __restrict__ dinv) {
    __shared__ int lds[256];
    int b = blockIdx.x;
    int h = b / 49;
    int tid = threadIdx.x;
    int w = (b % 49) * 256 + tid;
    unsigned dp = degp[h * WHALF + w];
    int lo = (int)(dp & 0xFFFFu), hi = (int)(dp >> 16);
    int s = lo + hi;
    lds[tid] = s;
    __syncthreads();
    #pragma unroll
    for (int off = 1; off < 256; off <<= 1) {
        int v = lds[tid];
        int add = (tid >= off) ? lds[tid - off] : 0;
        __syncthreads();
        lds[tid] = v + add;
        __syncthreads();
    }
    int excl = blk_off[b] + lds[tid] - s;
    int n0 = h * HALF_N + 2 * w;
    rs[n0] = excl;
    rs[n0 + 1] = excl + lo;
    deg[n0] = lo;
    deg[n0 + 1] = hi;
    dinv[n0] = (lo > 0) ? (1.0f / (float)lo) : 0.0f;
    dinv[n0 + 1] = (hi > 0) ? (1.0f / (float)hi) : 0.0f;
}

// ---------------- CSR fill: rank via LDS returning atomics; blockIdx.y = half ----------------
__global__ __launch_bounds__(256) void fill2(const int* __restrict__ src,
                                             const int* __restrict__ dst,
                                             const float* __restrict__ mask,
                                             const unsigned* __restrict__ cnt,
                                             const int* __restrict__ rs,
                                             unsigned* __restrict__ csr) {
    __shared__ unsigned cur[WHALF];   // 50 KB
    int c = blockIdx.x, h = blockIdx.y, tid = threadIdx.x;
    const unsigned* off = cnt + ((size_t)(h * NCHUNK + c)) * WHALF;
    for (int w = tid; w < WHALF; w += 256) cur[w] = off[w];
    __syncthreads();
    int base = c * CE;
    for (int k = tid; k < CE; k += 256) {
        int e = base + k;
        int d = dst[e];
        int local = d - h * HALF_N;
        if (local >= 0 && local < HALF_N) {
            unsigned sm = (unsigned)src[e] | ((unsigned)f2b(mask[e]) << 16);
            int sh = (local & 1) * 16;
            unsigned old = atomicAdd(&cur[local >> 1], 1u << sh);
            int rank = (int)((old >> sh) & 0xFFFFu);
            csr[rs[d] + rank] = sm;
        }
    }
}

// ---------------- mean aggregation: bf16 gather + f32 residual ----------------
__global__ __launch_bounds__(256) void agg_kernel(const unsigned short* __restrict__ xb,
                                                  const float* __restrict__ x,
                                                  float* __restrict__ xin,
                                                  const int* __restrict__ rs,
                                                  const int* __restrict__ deg,
                                                  const float* __restrict__ dinv,
                                                  const unsigned* __restrict__ csr) {
    int lane = threadIdx.x & 63;
    int node = blockIdx.x * 4 + (threadIdx.x >> 6);
    if (node >= N_NODES) return;
    int cnt = deg[node];
    int start = rs[node];
    float acc0 = 0.f, acc1 = 0.f;
    for (int base = 0; base < cnt; base += 16) {
        int nb = cnt - base;
        if (nb > 16) nb = 16;
        unsigned pk = 0;
        if (lane < nb) pk = csr[start + base + lane];
        unsigned vv[16];
        float mm[16];
        #pragma unroll
        for (int j = 0; j < 16; ++j) {
            unsigned p = (unsigned)__builtin_amdgcn_readlane((int)pk, j);  // 0 for j>=nb
            mm[j] = b2f((unsigned short)(p >> 16));
            vv[j] = *(const unsigned*)(xb + (size_t)(p & 0xFFFFu) * DIM + lane * 2);
        }
        #pragma unroll
        for (int j = 0; j < 16; ++j) {
            acc0 += mm[j] * b2f((unsigned short)(vv[j] & 0xFFFFu));
            acc1 += mm[j] * b2f((unsigned short)(vv[j] >> 16));
        }
    }
    float di = dinv[node];
    float2 xp = *(const float2*)(x + (size_t)node * DIM + lane * 2);
    float2 o;
    o.x = xp.x + acc0 * di;
    o.y = xp.y + acc1 * di;
    *(float2*)(xin + (size_t)node * DIM + lane * 2) = o;
}

// ---------------- GEMM [N,128]x[128,128] + BN + ReLU, split-bf16 MFMA ----------------
// B fragments loaded straight from global fragment-order buffers (L2-resident, no LDS)
__global__ __launch_bounds__(256) void gemm128_bn_relu(const float* __restrict__ xin,
                                                       const unsigned short* __restrict__ wfh,
                                                       const unsigned short* __restrict__ wfl,
                                                       const float* __restrict__ bias,
                                                       const float* __restrict__ gam,
                                                       const float* __restrict__ bet,
                                                       const float* __restrict__ rm,
                                                       const float* __restrict__ rv,
                                                       float* __restrict__ out,
                                                       unsigned short* __restrict__ outb) {
    int tid = threadIdx.x;
    int wave = tid >> 6, lane = tid & 63;
    int m = lane & 15, quad = lane >> 4;
    int rbase = blockIdx.x * 64 + wave * 16;
    int arow = rbase + m;
    const float* ap = xin + (size_t)(arow < N_NODES ? arow : 0) * DIM;

    us8_t ah[4], al[4];
    #pragma unroll
    for (int kt = 0; kt < 4; ++kt) {
        f32x4_t p0 = *(const f32x4_t*)(ap + kt * 32 + quad * 8);
        f32x4_t p1 = *(const f32x4_t*)(ap + kt * 32 + quad * 8 + 4);
        #pragma unroll
        for (int j = 0; j < 4; ++j) {
            unsigned short h0 = f2b(p0[j]);
            unsigned short h1 = f2b(p1[j]);
            ah[kt][j] = h0;
            ah[kt][4 + j] = h1;
            al[kt][j] = f2b(p0[j] - b2f(h0));
            al[kt][4 + j] = f2b(p1[j] - b2f(h1));
        }
    }

    f32x4_t acc[8] = {};
    #pragma unroll
    for (int kt = 0; kt < 4; ++kt) {
        #pragma unroll
        for (int nt = 0; nt < 8; ++nt) {
            int boff = ((nt * 4 + kt) * 64 + lane) * 8;
            us8_t bh = *(const us8_t*)(wfh + boff);
            us8_t bl = *(const us8_t*)(wfl + boff);
            acc[nt] = __builtin_amdgcn_mfma_f32_16x16x32_bf16(
                __builtin_bit_cast(bf16x8_t, ah[kt]),
                __builtin_bit_cast(bf16x8_t, bh), acc[nt], 0, 0, 0);
            acc[nt] = __builtin_amdgcn_mfma_f32_16x16x32_bf16(
                __builtin_bit_cast(bf16x8_t, ah[kt]),
                __builtin_bit_cast(bf16x8_t, bl), acc[nt], 0, 0, 0);
            acc[nt] = __builtin_amdgcn_mfma_f32_16x16x32_bf16(
                __builtin_bit_cast(bf16x8_t, al[kt]),
                __builtin_bit_cast(bf16x8_t, bh), acc[nt], 0, 0, 0);
        }
    }

    #pragma unroll
    for (int nt = 0; nt < 8; ++nt) {
        int j = nt * 16 + m;
        float bj = bias[j];
        float sc = gam[j] * rsqrtf(rv[j] + 1e-5f);
        float sh = bet[j] - rm[j] * sc;
        #pragma unroll
        for (int i = 0; i < 4; ++i) {
            int r = rbase + quad * 4 + i;
            if (r < N_NODES) {
                float z = fmaxf((acc[nt][i] + bj) * sc + sh, 0.f);
                out[(size_t)r * DIM + j] = z;
                outb[(size_t)r * DIM + j] = f2b(z);
            }
        }
    }
}

// ---------------- fused final: h3 = relu(BN((h2+agg)@w2+b2)); out = (h2@wp+bp+h3)*0.5 ----------------
__global__ __launch_bounds__(256) void fused_final(const float* __restrict__ xin2,
                                                   const float* __restrict__ h2,
                                                   const unsigned short* __restrict__ f2h,
                                                   const unsigned short* __restrict__ f2l,
                                                   const unsigned short* __restrict__ fph,
                                                   const unsigned short* __restrict__ fpl,
                                                   const float* __restrict__ b2,
                                                   const float* __restrict__ g2,
                                                   const float* __restrict__ be2,
                                                   const float* __restrict__ rm2,
                                                   const float* __restrict__ rv2,
                                                   const float* __restrict__ bp,
                                                   float* __restrict__ out) {
    int tid = threadIdx.x;
    int wave = tid >> 6, lane = tid & 63;
    int m = lane & 15, quad = lane >> 4;
    int rbase = blockIdx.x * 64 + wave * 16;
    int arow = rbase + m;
    size_t rowoff = (size_t)(arow < N_NODES ? arow : 0) * DIM;
    const float* ap2 = xin2 + rowoff;
    const float* aph = h2 + rowoff;

    us8_t a2h[4], a2l[4], ahh[4], ahl[4];
    #pragma unroll
    for (int kt = 0; kt < 4; ++kt) {
        f32x4_t p0 = *(const f32x4_t*)(ap2 + kt * 32 + quad * 8);
        f32x4_t p1 = *(const f32x4_t*)(ap2 + kt * 32 + quad * 8 + 4);
        f32x4_t q0 = *(const f32x4_t*)(aph + kt * 32 + quad * 8);
        f32x4_t q1 = *(const f32x4_t*)(aph + kt * 32 + quad * 8 + 4);
        #pragma unroll
        for (int j = 0; j < 4; ++j) {
            unsigned short h0 = f2b(p0[j]), h1 = f2b(p1[j]);
            a2h[kt][j] = h0; a2h[kt][4 + j] = h1;
            a2l[kt][j] = f2b(p0[j] - b2f(h0));
            a2l[kt][4 + j] = f2b(p1[j] - b2f(h1));
            unsigned short g0 = f2b(q0[j]), g1 = f2b(q1[j]);
            ahh[kt][j] = g0; ahh[kt][4 + j] = g1;
            ahl[kt][j] = f2b(q0[j] - b2f(g0));
            ahl[kt][4 + j] = f2b(q1[j] - b2f(g1));
        }
    }

    f32x4_t acc2[3] = {};
    f32x4_t accp[3] = {};
    #pragma unroll
    for (int kt = 0; kt < 4; ++kt) {
        #pragma unroll
        for (int nt = 0; nt < 3; ++nt) {
            int boff = ((nt * 4 + kt) * 64 + lane) * 8;
            us8_t b2hv = *(const us8_t*)(f2h + boff);
            us8_t b2lv = *(const us8_t*)(f2l + boff);
            us8_t bphv = *(const us8_t*)(fph + boff);
            us8_t bplv = *(const us8_t*)(fpl + boff);
            acc2[nt] = __builtin_amdgcn_mfma_f32_16x16x32_bf16(
                __builtin_bit_cast(bf16x8_t, a2h[kt]),
                __builtin_bit_cast(bf16x8_t, b2hv), acc2[nt], 0, 0, 0);
            acc2[nt] = __builtin_amdgcn_mfma_f32_16x16x32_bf16(
                __builtin_bit_cast(bf16x8_t, a2h[kt]),
                __builtin_bit_cast(bf16x8_t, b2lv), acc2[nt], 0, 0, 0);
            acc2[nt] = __builtin_amdgcn_mfma_f32_16x16x32_bf16(
                __builtin_bit_cast(bf16x8_t, a2l[kt]),
                __builtin_bit_cast(bf16x8_t, b2hv), acc2[nt], 0, 0, 0);
            accp[nt] = __builtin_amdgcn_mfma_f32_16x16x32_bf16(
                __builtin_bit_cast(bf16x8_t, ahh[kt]),
                __builtin_bit_cast(bf16x8_t, bphv), accp[nt], 0, 0, 0);
            accp[nt] = __builtin_amdgcn_mfma_f32_16x16x32_bf16(
                __builtin_bit_cast(bf16x8_t, ahh[kt]),
                __builtin_bit_cast(bf16x8_t, bplv), accp[nt], 0, 0, 0);
            accp[nt] = __builtin_amdgcn_mfma_f32_16x16x32_bf16(
                __builtin_bit_cast(bf16x8_t, ahl[kt]),
                __builtin_bit_cast(bf16x8_t, bphv), accp[nt], 0, 0, 0);
        }
    }

    #pragma unroll
    for (int nt = 0; nt < 3; ++nt) {
        int j = nt * 16 + m;
        int jc = (j < NCLS) ? j : (NCLS - 1);
        float b2j = b2[jc];
        float sc = g2[jc] * rsqrtf(rv2[jc] + 1e-5f);
        float sh = be2[jc] - rm2[jc] * sc;
        float bpj = bp[jc];
        #pragma unroll
        for (int i = 0; i < 4; ++i) {
            int r = rbase + quad * 4 + i;
            if (r < N_NODES && j < NCLS) {
                float z = fmaxf((acc2[nt][i] + b2j) * sc + sh, 0.f);
                float p = accp[nt][i] + bpj;
                out[(size_t)r * NCLS + j] = (p + z) * 0.5f;
            }
        }
    }
}

extern "C" void kernel_launch(void* const* d_in, const int* in_sizes, int n_in,
                              void* d_out, int out_size, void* d_ws, size_t ws_size,
                              hipStream_t stream) {
    const float* h    = (const float*)d_in[0];
    const int* esrc   = (const int*)d_in[1];
    const int* edst   = (const int*)d_in[2];
    const float* mask = (const float*)d_in[3];
    const float* w0   = (const float*)d_in[4];
    const float* b0   = (const float*)d_in[5];
    const float* g0   = (const float*)d_in[6];
    const float* be0  = (const float*)d_in[7];
    const float* rm0  = (const float*)d_in[8];
    const float* rv0  = (const float*)d_in[9];
    const float* w1   = (const float*)d_in[10];
    const float* b1   = (const float*)d_in[11];
    const float* g1   = (const float*)d_in[12];
    const float* be1  = (const float*)d_in[13];
    const float* rm1  = (const float*)d_in[14];
    const float* rv1  = (const float*)d_in[15];
    const float* w2   = (const float*)d_in[16];
    const float* b2   = (const float*)d_in[17];
    const float* g2   = (const float*)d_in[18];
    const float* be2  = (const float*)d_in[19];
    const float* rm2  = (const float*)d_in[20];
    const float* rv2  = (const float*)d_in[21];
    const float* wp   = (const float*)d_in[22];
    const float* bp   = (const float*)d_in[23];

    char* ws = (char*)d_ws;
    size_t off = 0;
    auto alloc = [&](size_t bytes) {
        char* p = ws + off;
        off = (off + bytes + 255) & ~(size_t)255;
        return p;
    };
    int* rs       = (int*)alloc(N_PAD * 4);
    int* deg      = (int*)alloc(N_PAD * 4);
    float* dinv   = (float*)alloc(N_PAD * 4);
    int* partial  = (int*)alloc(128 * 4);
    int* blk_off  = (int*)alloc(128 * 4);
    unsigned* degp = (unsigned*)alloc(2 * WHALF * 4);
    unsigned* csr = (unsigned*)alloc((size_t)N_EDGES * 4);
    float* xin    = (float*)alloc((size_t)N_NODES * DIM * 4);
    float* hb     = (float*)alloc((size_t)N_NODES * DIM * 4);
    unsigned short* xb16 = (unsigned short*)alloc((size_t)N_NODES * DIM * 2);
    unsigned short* hb16 = (unsigned short*)alloc((size_t)N_NODES * DIM * 2);
    unsigned short* f0h = (unsigned short*)alloc(16384 * 2);
    unsigned short* f0l = (unsigned short*)alloc(16384 * 2);
    unsigned short* f1h = (unsigned short*)alloc(16384 * 2);
    unsigned short* f1l = (unsigned short*)alloc(16384 * 2);
    unsigned short* f2h = (unsigned short*)alloc(6144 * 2);
    unsigned short* f2l = (unsigned short*)alloc(6144 * 2);
    unsigned short* fph = (unsigned short*)alloc(6144 * 2);
    unsigned short* fpl = (unsigned short*)alloc(6144 * 2);
    // cnt (12.85 MB) aliases xin (25.6 MB): fully consumed by fill2 before agg writes xin
    unsigned* cnt = (unsigned*)xin;

    const int AB = (N_NODES + 3) / 4;
    const int GB = (N_NODES + 63) / 64;

    to_bf16<<<3125, 256, 0, stream>>>(h, xb16);
    repack_w<<<176, 256, 0, stream>>>(w0, w1, w2, wp, f0h, f0l, f1h, f1l,
                                      f2h, f2l, fph, fpl);
    chunk_count<<<dim3(NCHUNK, 2), 256, 0, stream>>>(edst, cnt);
    cscan<<<SCAN_B, 256, 0, stream>>>(cnt, degp, partial);
    scan_blocks<<<1, 128, 0, stream>>>(partial, blk_off);
    scan_final<<<SCAN_B, 256, 0, stream>>>(degp, blk_off, rs, deg, dinv);
    fill2<<<dim3(NCHUNK, 2), 256, 0, stream>>>(esrc, edst, mask, cnt, rs, csr);

    // layer 0
    agg_kernel<<<AB, 256, 0, stream>>>(xb16, h, xin, rs, deg, dinv, csr);
    gemm128_bn_relu<<<GB, 256, 0, stream>>>(xin, f0h, f0l, b0, g0, be0, rm0, rv0, hb, hb16);
    // layer 1
    agg_kernel<<<AB, 256, 0, stream>>>(hb16, hb, xin, rs, deg, dinv, csr);
    gemm128_bn_relu<<<GB, 256, 0, stream>>>(xin, f1h, f1l, b1, g1, be1, rm1, rv1, hb, hb16);
    // layer 2 + predict, fused
    agg_kernel<<<AB, 256, 0, stream>>>(hb16, hb, xin, rs, deg, dinv, csr);
    fused_final<<<GB, 256, 0, stream>>>(xin, hb, f2h, f2l, fph, fpl,
                                        b2, g2, be2, rm2, rv2, bp, (float*)d_out);
}